// Round 7
// baseline (861.710 us; speedup 1.0000x reference)
//
#include <hip/hip_runtime.h>

#define D      128
#define NCLI   100000
#define NAGG   1000
#define NLAYER 3
#define NBKT   782   // ceil(NCLI/128) buckets for a2c
#define NRNG   8     // src ranges for c2a CSR (12500 clients each, 3.2 MB slice/XCD-L2)
#define NBIN   (NAGG * NRNG)   // 8000
#define RMAGIC 343598u         // ceil(2^32/12500): r = umulhi(src, RMAGIC), exact for src<100000
#define NHIST  512
#define NCVTX  (NCLI * D / 4 / 256)   // 12500
#define NCVTW  ((NLAYER * D * D + 255) / 256)  // 192
#define NROWT  (NCLI / 32)            // 3125 row-tiles (exact)
#define CAP_E  1536   // per-block col prefetch capacity (mean 512; huge headroom)

typedef short bf16x8 __attribute__((ext_vector_type(8)));
typedef float f32x16 __attribute__((ext_vector_type(16)));

typedef __attribute__((address_space(1))) const unsigned g_u32;
typedef __attribute__((address_space(3))) unsigned l_u32;

static __device__ __forceinline__ float leaky(float x) { return x >= 0.f ? x : 0.1f * x; }

// ---- bf16 pack/unpack (RNE) ----
static __device__ __forceinline__ unsigned bf16_rn(float f) {
    unsigned u = __float_as_uint(f);
    return (u + 0x7fffu + ((u >> 16) & 1u)) >> 16;
}
static __device__ __forceinline__ float bf_val(unsigned h) { return __uint_as_float(h << 16); }
static __device__ __forceinline__ unsigned pack_bf2(float lo, float hi) {
    return bf16_rn(lo) | (bf16_rn(hi) << 16);
}
static __device__ __forceinline__ float bf_lo(unsigned v) { return __uint_as_float(v << 16); }
static __device__ __forceinline__ float bf_hi(unsigned v) { return __uint_as_float(v & 0xffff0000u); }

// ---------------- phase 1: hist + feature/weight cvt, one launch ----------------
__global__ __launch_bounds__(256) void prep(const int* __restrict__ c2a_src,
                                            const int* __restrict__ c2a_dst,
                                            const int* __restrict__ a2c_dst, int E,
                                            int* __restrict__ cnt_ar, int* __restrict__ bcnt,
                                            const float4* __restrict__ X4,
                                            uint2* __restrict__ xhi, uint2* __restrict__ xlo,
                                            const float* __restrict__ W,
                                            unsigned short* __restrict__ Wt) {
    __shared__ int h[NBIN + NBKT];   // 35 KB
    int bid = blockIdx.x;
    if (bid < NHIST) {
        for (int i = threadIdx.x; i < NBIN + NBKT; i += 256) h[i] = 0;
        __syncthreads();
        int stride = NHIST * 256;
        for (int e = bid * 256 + threadIdx.x; e < E; e += stride) {
            int s = c2a_src[e];
            int bin = c2a_dst[e] * NRNG + (int)__umulhi((unsigned)s, RMAGIC);
            atomicAdd(&h[bin], 1);
            atomicAdd(&h[NBIN + (a2c_dst[e] >> 7)], 1);
        }
        __syncthreads();
        for (int i = threadIdx.x; i < NBIN; i += 256)
            if (h[i]) atomicAdd(&cnt_ar[i], h[i]);
        for (int i = threadIdx.x; i < NBKT; i += 256)
            if (h[NBIN + i]) atomicAdd(&bcnt[i], h[NBIN + i]);
    } else if (bid < NHIST + NCVTX) {
        int t = (bid - NHIST) * 256 + threadIdx.x;
        float4 f = X4[t];
        unsigned h0 = bf16_rn(f.x), h1 = bf16_rn(f.y), h2 = bf16_rn(f.z), h3 = bf16_rn(f.w);
        xhi[t] = make_uint2(h0 | (h1 << 16), h2 | (h3 << 16));
        xlo[t] = make_uint2(pack_bf2(f.x - bf_val(h0), f.y - bf_val(h1)),
                            pack_bf2(f.z - bf_val(h2), f.w - bf_val(h3)));
    } else {
        int idx = (bid - NHIST - NCVTX) * 256 + threadIdx.x;
        if (idx >= NLAYER * D * D) return;
        int layer = idx >> 14, rem = idx & (D * D - 1);
        int k = rem >> 7, n = rem & 127;
        float w = W[layer * D * D + k * D + n];
        unsigned hh = bf16_rn(w);
        unsigned short* base = Wt + layer * 2 * D * D;
        base[n * D + k] = (unsigned short)hh;
        base[D * D + n * D + k] = (unsigned short)bf16_rn(w - bf_val(hh));
    }
}

// ---------------- phase 2: scans ----------------
__global__ void scan_both(const int* __restrict__ cnt_ar, int* __restrict__ rp_ar,
                          int* __restrict__ cur_ar, const int* __restrict__ bcnt,
                          int* __restrict__ brp, int* __restrict__ bcur) {
    __shared__ int sh[1024];
    int t = threadIdx.x;
    if (blockIdx.x == 0) {
        int v[8];
        int s = 0;
#pragma unroll
        for (int j = 0; j < 8; j++) {
            int idx = t * 8 + j;
            v[j] = (idx < NBIN) ? cnt_ar[idx] : 0;
            s += v[j];
        }
        sh[t] = s;
        __syncthreads();
        for (int off = 1; off < 1024; off <<= 1) {
            int x = (t >= off) ? sh[t - off] : 0;
            __syncthreads();
            sh[t] += x;
            __syncthreads();
        }
        int run = sh[t] - s;  // exclusive prefix of this thread's chunk
#pragma unroll
        for (int j = 0; j < 8; j++) {
            int idx = t * 8 + j;
            if (idx < NBIN) {
                rp_ar[idx] = run;
                cur_ar[idx] = run;
            }
            run += v[j];
        }
        if (t == 1023) rp_ar[NBIN] = sh[1023];
    } else {
        int v = (t < NBKT) ? bcnt[t] : 0;
        sh[t] = v;
        __syncthreads();
        for (int off = 1; off < 1024; off <<= 1) {
            int x = (t >= off) ? sh[t - off] : 0;
            __syncthreads();
            sh[t] += x;
            __syncthreads();
        }
        if (t == 0) { brp[0] = 0; bcur[0] = 0; }
        if (t < NBKT) {
            brp[t + 1] = sh[t];
            if (t + 1 < NBKT) bcur[t + 1] = sh[t];
        }
    }
}

// ---------------- phase 3: both scatters, one launch, 1024 threads ----------------
__global__ __launch_bounds__(1024) void scatter_both(const int* __restrict__ c2a_src,
                                                     const int* __restrict__ c2a_dst,
                                                     const int* __restrict__ a2c_src,
                                                     const int* __restrict__ a2c_dst, int E,
                                                     int* __restrict__ cur_ar,
                                                     int* __restrict__ col_c2a,
                                                     int* __restrict__ bcur,
                                                     int* __restrict__ sorted1) {
    __shared__ int sbuf[2 * NBIN];   // 64 KB; a2c half reuses the front
    int tid = threadIdx.x;
    if (blockIdx.x < 256) {
        int* h = sbuf;
        int* base = sbuf + NBIN;
        int chunk = (E + 255) / 256;
        int e0 = blockIdx.x * chunk;
        int e1 = min(E, e0 + chunk);
        for (int i = tid; i < NBIN; i += 1024) h[i] = 0;
        __syncthreads();
        for (int e = e0 + tid; e < e1; e += 1024) {
            int s = c2a_src[e];
            atomicAdd(&h[c2a_dst[e] * NRNG + (int)__umulhi((unsigned)s, RMAGIC)], 1);
        }
        __syncthreads();
        for (int i = tid; i < NBIN; i += 1024) {
            int c = h[i];
            base[i] = c ? atomicAdd(&cur_ar[i], c) : 0;
        }
        __syncthreads();
        for (int e = e0 + tid; e < e1; e += 1024) {
            int s = c2a_src[e];
            int bin = c2a_dst[e] * NRNG + (int)__umulhi((unsigned)s, RMAGIC);
            int pos = atomicAdd(&base[bin], 1);
            col_c2a[pos] = s;
        }
    } else {
        int* h = sbuf;
        int* base = sbuf + NBKT;
        int bid = blockIdx.x - 256;
        int chunk = (E + 255) / 256;
        int e0 = bid * chunk;
        int e1 = min(E, e0 + chunk);
        for (int i = tid; i < NBKT; i += 1024) h[i] = 0;
        __syncthreads();
        for (int e = e0 + tid; e < e1; e += 1024) atomicAdd(&h[a2c_dst[e] >> 7], 1);
        __syncthreads();
        for (int i = tid; i < NBKT; i += 1024) {
            int c = h[i];
            base[i] = c ? atomicAdd(&bcur[i], c) : 0;
        }
        __syncthreads();
        for (int e = e0 + tid; e < e1; e += 1024) {
            int d = a2c_dst[e];
            int pos = atomicAdd(&base[d >> 7], 1);
            sorted1[pos] = ((d & 127) << 10) | a2c_src[e];
        }
    }
}

// ---------------- phase 4: per-bucket client CSR (a2c) ----------------
__global__ __launch_bounds__(512) void bucket_csr(const int* __restrict__ brp,
                                                  const int* __restrict__ sorted1,
                                                  int* __restrict__ rp_c,
                                                  int* __restrict__ col) {
    __shared__ int h[128], cur[128];
    int b = blockIdx.x, tid = threadIdx.x;
    if (tid < 128) h[tid] = 0;
    __syncthreads();
    int beg = brp[b], end = brp[b + 1];
    for (int e = beg + tid; e < end; e += 512) atomicAdd(&h[sorted1[e] >> 10], 1);
    __syncthreads();
    if (tid < 128) cur[tid] = h[tid];
    __syncthreads();
    for (int off = 1; off < 128; off <<= 1) {
        int x = 0;
        if (tid < 128 && tid >= off) x = cur[tid - off];
        __syncthreads();
        if (tid < 128) cur[tid] += x;
        __syncthreads();
    }
    if (tid < 128) {
        int start = beg + cur[tid] - h[tid];
        int c = b * 128 + tid;
        if (c < NCLI) rp_c[c] = start;
        cur[tid] = start;
    }
    if (b == NBKT - 1 && tid == 0) rp_c[NCLI] = end;
    __syncthreads();
    for (int e = beg + tid; e < end; e += 512) {
        int p = sorted1[e];
        int pos = atomicAdd(&cur[p >> 10], 1);
        col[pos] = p & 1023;
    }
}

// ---------------- layer kernels ----------------

// XCD-sliced mean gather (unchanged).
__global__ __launch_bounds__(512) void gather_mean(const unsigned* __restrict__ tbl,
                                                   const int* __restrict__ rp_ar,
                                                   const int* __restrict__ col,
                                                   float* __restrict__ psum) {
    __shared__ float part[4][8][D];   // 16 KB
    int quad = blockIdx.x >> 3, r = blockIdx.x & 7;
    int tid = threadIdx.x;
    int a = tid >> 7;            // local agg 0..3
    int sub = (tid >> 4) & 7;    // reader 0..7
    int sl = tid & 15;           // lane in reader
    const uint4* tbl4 = (const uint4*)tbl;
    int agg = quad * 4 + a;
    int bin = agg * NRNG + r;
    int beg = rp_ar[bin], end = rp_ar[bin + 1];
    float f0 = 0, f1 = 0, f2 = 0, f3 = 0, f4 = 0, f5 = 0, f6 = 0, f7 = 0;
    int e = beg + sub;
    for (; e + 8 < end; e += 16) {   // 2 edges in flight per reader
        int s0 = col[e];
        int s1 = col[e + 8];
        uint4 v0 = tbl4[(s0 << 4) + sl];
        uint4 v1 = tbl4[(s1 << 4) + sl];
        f0 += bf_lo(v0.x); f1 += bf_hi(v0.x); f2 += bf_lo(v0.y); f3 += bf_hi(v0.y);
        f4 += bf_lo(v0.z); f5 += bf_hi(v0.z); f6 += bf_lo(v0.w); f7 += bf_hi(v0.w);
        f0 += bf_lo(v1.x); f1 += bf_hi(v1.x); f2 += bf_lo(v1.y); f3 += bf_hi(v1.y);
        f4 += bf_lo(v1.z); f5 += bf_hi(v1.z); f6 += bf_lo(v1.w); f7 += bf_hi(v1.w);
    }
    if (e < end) {
        int s0 = col[e];
        uint4 v0 = tbl4[(s0 << 4) + sl];
        f0 += bf_lo(v0.x); f1 += bf_hi(v0.x); f2 += bf_lo(v0.y); f3 += bf_hi(v0.y);
        f4 += bf_lo(v0.z); f5 += bf_hi(v0.z); f6 += bf_lo(v0.w); f7 += bf_hi(v0.w);
    }
    float* pr = &part[a][sub][sl * 8];
    pr[0] = f0; pr[1] = f1; pr[2] = f2; pr[3] = f3;
    pr[4] = f4; pr[5] = f5; pr[6] = f6; pr[7] = f7;
    __syncthreads();
    int c = tid & 127;
    float s = 0.f;
#pragma unroll
    for (int g = 0; g < 8; g++) s += part[a][g][c];
    psum[((size_t)agg * NRNG + r) * D + c] = s;
}

// combine partials -> mean; then ya = xa@Wl_a2c (bf16 row-major), xa_new = leaky(...)
__global__ __launch_bounds__(128) void combine_agg(const float* __restrict__ psum,
                                                   const int* __restrict__ rp_ar,
                                                   const float* xa_old,
                                                   const float* __restrict__ Wl_a2c,
                                                   const float* __restrict__ Wl_c2a,
                                                   const float* __restrict__ Wr_c2a,
                                                   const float* __restrict__ b_c2a,
                                                   unsigned short* __restrict__ ya_bf,
                                                   float* xa_out) {
    __shared__ float mr[D], xr[D];
    int i = blockIdx.x, j = threadIdx.x;
    const float* pr = psum + (size_t)i * NRNG * D + j;
    float s = 0.f;
#pragma unroll
    for (int r = 0; r < NRNG; r++) s += pr[r * D];
    int deg = rp_ar[i * NRNG + NRNG] - rp_ar[i * NRNG];
    mr[j] = s / fmaxf((float)deg, 1.f);
    xr[j] = xa_old[i * D + j];
    __syncthreads();
    float accy = 0.f, accn = b_c2a[j];
#pragma unroll 4
    for (int k = 0; k < D; k++) {
        accy += xr[k] * Wl_a2c[k * D + j];
        accn += mr[k] * Wl_c2a[k * D + j] + xr[k] * Wr_c2a[k * D + j];
    }
    ya_bf[i * D + j] = (unsigned short)bf16_rn(accy);
    xa_out[i * D + j] = leaky(accn);
}

// FUSED gemm+agg, R7: ya rows fetched via ASYNC global_load_lds (no VGPR result,
// no dependence chain the compiler can serialize). One instruction per edge: 64
// lanes each pull dword `lane` of the row -> 256B row lands in a per-wave LDS slot.
// Double-buffered 8-edge chunks with counted s_waitcnt vmcnt(8) (never 0 in-stream).
// Consume reads word `lane` (2 lanes/bank, conflict-free). R2-R6 all plateaued at
// ~90-110us with 25-35% VALUBusy: per-block latency was 8x the work+latency model,
// consistent only with compiler-serialized load->use chains; async DMA removes them.
template <int LAST>
__global__ __launch_bounds__(256) void gemm_agg(const unsigned short* __restrict__ Ahi,
                                                const unsigned short* __restrict__ Alo,
                                                const unsigned short* __restrict__ Wt,
                                                const float* __restrict__ bias,
                                                const unsigned* __restrict__ ya,  // [NAGG][64] words
                                                const int* __restrict__ rowptr,
                                                const int* __restrict__ col,
                                                unsigned* __restrict__ xhi,
                                                unsigned* __restrict__ xlo,
                                                const float* __restrict__ Wlin,
                                                const float* __restrict__ blin,
                                                float* __restrict__ out, int E) {
    __shared__ float smem[32][D];            // 16 KB gemm output tile
    __shared__ unsigned abuf[4][2][8][64];   // 16 KB async row staging (wave-private)
    __shared__ int lcol[CAP_E];              // 6 KB col slice
    __shared__ int lrp[33];                  // block rowptr slice
    int tid = threadIdx.x;
    int wave = tid >> 6, lane = tid & 63;
    int cl = lane & 31, kh = lane >> 5;
    int n0 = wave * 32;
    int m0 = blockIdx.x * 32;
    int blkBeg = rowptr[m0], blkEnd = rowptr[m0 + 32];
    int nE = blkEnd - blkBeg;
    bool inlds = (nE <= CAP_E);
    // col-slice prefetch issued FIRST: HBM/L2 latency hides under gemm
    int pv[6];
#pragma unroll
    for (int k = 0; k < 6; k++) pv[k] = col[min(blkBeg + tid + k * 256, E - 1)];
    if (tid < 33) lrp[tid] = rowptr[m0 + tid];
    // gemm1: Y = xc @ W + bias
    float bv = bias[n0 + cl];
    f32x16 acc1;
#pragma unroll
    for (int qq = 0; qq < 16; qq++) acc1[qq] = bv;
    {
        const unsigned short* Wlo_ = Wt + D * D;
        const unsigned short* ar = Ahi + (size_t)(m0 + cl) * D + kh * 8;
        const unsigned short* al = Alo + (size_t)(m0 + cl) * D + kh * 8;
        const unsigned short* wh = Wt + (size_t)(n0 + cl) * D + kh * 8;
        const unsigned short* wl = Wlo_ + (size_t)(n0 + cl) * D + kh * 8;
        if (inlds) {
#pragma unroll
            for (int k = 0; k < 6; k++) lcol[tid + k * 256] = pv[k];
        }
#pragma unroll
        for (int kc = 0; kc < 8; kc++) {
            bf16x8 ahi = *(const bf16x8*)(ar + kc * 16);
            bf16x8 alo = *(const bf16x8*)(al + kc * 16);
            bf16x8 bh = *(const bf16x8*)(wh + kc * 16);
            bf16x8 bl = *(const bf16x8*)(wl + kc * 16);
            acc1 = __builtin_amdgcn_mfma_f32_32x32x16_bf16(ahi, bh, acc1, 0, 0, 0);
            acc1 = __builtin_amdgcn_mfma_f32_32x32x16_bf16(alo, bh, acc1, 0, 0, 0);
            acc1 = __builtin_amdgcn_mfma_f32_32x32x16_bf16(ahi, bl, acc1, 0, 0, 0);
        }
    }
#pragma unroll
    for (int reg = 0; reg < 16; reg++) {
        int row = (reg & 3) + 8 * (reg >> 2) + 4 * kh;
        smem[row][n0 + cl] = acc1[reg];   // 2 lanes/bank max -> conflict-free
    }
    __syncthreads();
    // ---- agg: wave streams its 8 clients' edges via async row staging ----
    const int w8 = wave * 8;
    int e0 = lrp[w8], eend = lrp[w8 + 8];
    int cli = 0;
    int nb = lrp[w8 + 1];
    float s0 = 0.f, s1 = 0.f;
    float wl0 = 0.f, wl1 = 0.f;
    if (LAST) { float2 wv = *(const float2*)&Wlin[2 * lane]; wl0 = wv.x; wl1 = wv.y; }
    auto flushc = [&]() {
        int c_local = w8 + cli;
        int gid = m0 + c_local;
        int deg = lrp[c_local + 1] - lrp[c_local];
        float inv = 1.f / fmaxf((float)deg, 1.f);
        float2 yv = *(const float2*)&smem[c_local][2 * lane];
        float r0 = leaky(yv.x + s0 * inv);
        float r1 = leaky(yv.y + s1 * inv);
        if (LAST) {
            float v = r0 * wl0 + r1 * wl1;
#pragma unroll
            for (int off = 32; off > 0; off >>= 1) v += __shfl_down(v, off);
            if (lane == 0) out[gid] = v + blin[0];
        } else {
            unsigned h0 = bf16_rn(r0), h1 = bf16_rn(r1);
            xhi[(gid << 6) + lane] = h0 | (h1 << 16);
            xlo[(gid << 6) + lane] = pack_bf2(r0 - bf_val(h0), r1 - bf_val(h1));
        }
        s0 = 0.f;
        s1 = 0.f;
    };
    auto stage = [&](int b, int base) {
        // prior ds_reads of this buffer have long retired; cheap insurance:
        asm volatile("s_waitcnt lgkmcnt(0)" ::: "memory");
#pragma unroll
        for (int j = 0; j < 8; j++) {
            int e = min(base + j, eend - 1);
            int idx = inlds ? lcol[e - blkBeg] : col[e];
            __builtin_amdgcn_global_load_lds((g_u32*)(ya + (idx << 6) + lane),
                                             (l_u32*)&abuf[wave][b][j][0], 4, 0, 0);
        }
    };
    auto consume = [&](int b, int ck) {
#pragma unroll
        for (int j = 0; j < 8; j++) {
            if (ck + j < eend) {
                while (ck + j == nb) {   // wave-uniform scalar boundary walk
                    flushc();
                    cli++;
                    nb = lrp[w8 + cli + 1];
                }
                unsigned v = abuf[wave][b][j][lane];
                s0 += bf_lo(v);
                s1 += bf_hi(v);
            }
        }
    };
    if (e0 < eend) {
        stage(0, e0);
        for (int ck = e0; ck < eend; ck += 16) {
            bool hasB = (ck + 8 < eend);
            if (hasB) {
                stage(1, ck + 8);
                asm volatile("s_waitcnt vmcnt(8)" ::: "memory");
            } else {
                asm volatile("s_waitcnt vmcnt(0)" ::: "memory");
            }
            __builtin_amdgcn_sched_barrier(0);
            consume(0, ck);
            if (hasB) {
                bool hasA2 = (ck + 16 < eend);
                if (hasA2) {
                    stage(0, ck + 16);
                    asm volatile("s_waitcnt vmcnt(8)" ::: "memory");
                } else {
                    asm volatile("s_waitcnt vmcnt(0)" ::: "memory");
                }
                __builtin_amdgcn_sched_barrier(0);
                consume(1, ck + 8);
            }
        }
    }
    while (cli < 8) {
        flushc();
        cli++;
    }
}

extern "C" void kernel_launch(void* const* d_in, const int* in_sizes, int n_in,
                              void* d_out, int out_size, void* d_ws, size_t ws_size,
                              hipStream_t stream) {
    const float* x_clients = (const float*)d_in[0];
    const float* x_agg     = (const float*)d_in[1];
    const int*   c2a_src   = (const int*)d_in[2];
    const int*   c2a_dst   = (const int*)d_in[3];
    const int*   a2c_src   = (const int*)d_in[4];
    const int*   a2c_dst   = (const int*)d_in[5];
    const float* Wl_c2a    = (const float*)d_in[6];
    const float* Wr_c2a    = (const float*)d_in[7];
    const float* b_c2a     = (const float*)d_in[8];
    const float* Wl_a2c    = (const float*)d_in[9];
    const float* Wr_a2c    = (const float*)d_in[10];
    const float* b_a2c     = (const float*)d_in[11];
    const float* W_lin     = (const float*)d_in[12];
    const float* b_lin     = (const float*)d_in[13];
    float* out = (float*)d_out;
    const int E = in_sizes[2];

    char* p = (char*)d_ws;
    auto alloc = [&](size_t bytes) {
        char* r = p;
        p += (bytes + 255) & ~(size_t)255;
        return r;
    };
    float*    Yb    = (float*)alloc(sizeof(float) * NCLI * D);         // sorted1 scratch only
    unsigned* xc_hi = (unsigned*)alloc(sizeof(unsigned) * NCLI * 64);  // bf16 hi (also gather tbl)
    unsigned* xc_lo = (unsigned*)alloc(sizeof(unsigned) * NCLI * 64);  // bf16 lo
    float*    xa    = (float*)alloc(sizeof(float) * NAGG * D);
    unsigned short* ya_bf = (unsigned short*)alloc(sizeof(unsigned short) * NAGG * D);
    unsigned short* Wt = (unsigned short*)alloc(sizeof(unsigned short) * NLAYER * 2 * D * D);
    float* psum  = (float*)alloc(sizeof(float) * NAGG * NRNG * D);     // 4 MB gather partials
    int* cnt_ar = (int*)alloc(sizeof(int) * (NBIN + NBKT));  // cnt_ar[0..7999] + bcnt
    int* bcnt  = cnt_ar + NBIN;
    int* rp_ar = (int*)alloc(sizeof(int) * (NBIN + 1));
    int* cur_ar = (int*)alloc(sizeof(int) * NBIN);
    int* brp   = (int*)alloc(sizeof(int) * (NBKT + 1));
    int* bcur  = (int*)alloc(sizeof(int) * NBKT);
    int* rp_c  = (int*)alloc(sizeof(int) * (NCLI + 1));
    int* col_c2a = (int*)alloc(sizeof(int) * E);
    int* col_a2c = (int*)alloc(sizeof(int) * E);
    // sorted1 aliases Yb: nothing writes Yb anymore (gemm output stays in LDS)
    int* sorted1 = (int*)Yb;

    hipMemsetAsync(cnt_ar, 0, sizeof(int) * (NBIN + NBKT), stream);

    prep<<<NHIST + NCVTX + NCVTW, 256, 0, stream>>>(c2a_src, c2a_dst, a2c_dst, E, cnt_ar, bcnt,
                                                    (const float4*)x_clients,
                                                    (uint2*)xc_hi, (uint2*)xc_lo,
                                                    Wr_a2c, Wt);
    scan_both<<<2, 1024, 0, stream>>>(cnt_ar, rp_ar, cur_ar, bcnt, brp, bcur);
    scatter_both<<<512, 1024, 0, stream>>>(c2a_src, c2a_dst, a2c_src, a2c_dst, E,
                                           cur_ar, col_c2a, bcur, sorted1);
    bucket_csr<<<NBKT, 512, 0, stream>>>(brp, sorted1, rp_c, col_a2c);

    const float* xa_old = x_agg;
    for (int l = 0; l < NLAYER; l++) {
        gather_mean<<<(NAGG / 4) * NRNG, 512, 0, stream>>>(xc_hi, rp_ar, col_c2a, psum);
        combine_agg<<<NAGG, 128, 0, stream>>>(psum, rp_ar, xa_old,
                                              Wl_a2c + l * D * D, Wl_c2a + l * D * D,
                                              Wr_c2a + l * D * D, b_c2a + l * D, ya_bf, xa);
        if (l < NLAYER - 1) {
            gemm_agg<0><<<NROWT, 256, 0, stream>>>(
                (const unsigned short*)xc_hi, (const unsigned short*)xc_lo,
                Wt + l * 2 * D * D, b_a2c + l * D, (const unsigned*)ya_bf, rp_c, col_a2c,
                xc_hi, xc_lo, nullptr, nullptr, nullptr, E);
        } else {
            gemm_agg<1><<<NROWT, 256, 0, stream>>>(
                (const unsigned short*)xc_hi, (const unsigned short*)xc_lo,
                Wt + l * 2 * D * D, b_a2c + l * D, (const unsigned*)ya_bf, rp_c, col_a2c,
                nullptr, nullptr, W_lin, b_lin, out, E);
        }
        xa_old = xa;
    }
}

// Round 8
// 598.013 us; speedup vs baseline: 1.4410x; 1.4410x over previous
//
#include <hip/hip_runtime.h>

#define D      128
#define NCLI   100000
#define NAGG   1000
#define NLAYER 3
#define NBKT   98    // coarse a2c buckets (dst>>10), 98*1024 >= 100000
#define NC2A   63    // coarse c2a buckets (bin>>7), 63*128 >= 8000
#define NRNG   8     // src ranges for c2a CSR (12500 clients each, 3.2 MB slice/XCD-L2)
#define NBIN   (NAGG * NRNG)   // 8000
#define RMAGIC 343598u         // ceil(2^32/12500): r = umulhi(src, RMAGIC), exact for src<100000
#define NHIST  512
#define NCVTX  (NCLI * D / 4 / 256)   // 12500
#define NCVTW  ((NLAYER * D * D + 255) / 256)  // 192
#define NROWT  (NCLI / 32)            // 3125 row-tiles (exact)
#define CAP_E  1536   // per-block col prefetch capacity (mean 512; huge headroom)

typedef short bf16x8 __attribute__((ext_vector_type(8)));
typedef float f32x16 __attribute__((ext_vector_type(16)));

static __device__ __forceinline__ float leaky(float x) { return x >= 0.f ? x : 0.1f * x; }

// ---- bf16 pack/unpack (RNE) ----
static __device__ __forceinline__ unsigned bf16_rn(float f) {
    unsigned u = __float_as_uint(f);
    return (u + 0x7fffu + ((u >> 16) & 1u)) >> 16;
}
static __device__ __forceinline__ float bf_val(unsigned h) { return __uint_as_float(h << 16); }
static __device__ __forceinline__ unsigned pack_bf2(float lo, float hi) {
    return bf16_rn(lo) | (bf16_rn(hi) << 16);
}
static __device__ __forceinline__ float bf_lo(unsigned v) { return __uint_as_float(v << 16); }
static __device__ __forceinline__ float bf_hi(unsigned v) { return __uint_as_float(v & 0xffff0000u); }

// ---------------- phase 1: hist + feature/weight cvt, one launch ----------------
__global__ __launch_bounds__(256) void prep(const int* __restrict__ c2a_src,
                                            const int* __restrict__ c2a_dst,
                                            const int* __restrict__ a2c_dst, int E,
                                            int* __restrict__ cnt_ar, int* __restrict__ bcnt,
                                            const float4* __restrict__ X4,
                                            uint2* __restrict__ xhi, uint2* __restrict__ xlo,
                                            const float* __restrict__ W,
                                            unsigned short* __restrict__ Wt) {
    __shared__ int h[NBIN + NBKT];   // 32.4 KB
    int bid = blockIdx.x;
    if (bid < NHIST) {
        for (int i = threadIdx.x; i < NBIN + NBKT; i += 256) h[i] = 0;
        __syncthreads();
        int stride = NHIST * 256;
        for (int e = bid * 256 + threadIdx.x; e < E; e += stride) {
            int s = c2a_src[e];
            int bin = c2a_dst[e] * NRNG + (int)__umulhi((unsigned)s, RMAGIC);
            atomicAdd(&h[bin], 1);
            atomicAdd(&h[NBIN + (a2c_dst[e] >> 10)], 1);
        }
        __syncthreads();
        for (int i = threadIdx.x; i < NBIN; i += 256)
            if (h[i]) atomicAdd(&cnt_ar[i], h[i]);
        for (int i = threadIdx.x; i < NBKT; i += 256)
            if (h[NBIN + i]) atomicAdd(&bcnt[i], h[NBIN + i]);
    } else if (bid < NHIST + NCVTX) {
        int t = (bid - NHIST) * 256 + threadIdx.x;
        float4 f = X4[t];
        unsigned h0 = bf16_rn(f.x), h1 = bf16_rn(f.y), h2 = bf16_rn(f.z), h3 = bf16_rn(f.w);
        xhi[t] = make_uint2(h0 | (h1 << 16), h2 | (h3 << 16));
        xlo[t] = make_uint2(pack_bf2(f.x - bf_val(h0), f.y - bf_val(h1)),
                            pack_bf2(f.z - bf_val(h2), f.w - bf_val(h3)));
    } else {
        int idx = (bid - NHIST - NCVTX) * 256 + threadIdx.x;
        if (idx >= NLAYER * D * D) return;
        int layer = idx >> 14, rem = idx & (D * D - 1);
        int k = rem >> 7, n = rem & 127;
        float w = W[layer * D * D + k * D + n];
        unsigned hh = bf16_rn(w);
        unsigned short* base = Wt + layer * 2 * D * D;
        base[n * D + k] = (unsigned short)hh;
        base[D * D + n * D + k] = (unsigned short)bf16_rn(w - bf_val(hh));
    }
}

// ---------------- phase 2: scans ----------------
// block 0: scan cnt_ar[8000] -> rp_ar[8001]; then ccur[c] = rp_ar[c*128] (c2a coarse cursors)
// block 1: scan bcnt[98] -> brp[99] + bcur[98]
__global__ void scan_both(const int* __restrict__ cnt_ar, int* __restrict__ rp_ar,
                          const int* __restrict__ bcnt,
                          int* __restrict__ brp, int* __restrict__ bcur,
                          int* __restrict__ ccur) {
    __shared__ int sh[1024];
    int t = threadIdx.x;
    if (blockIdx.x == 0) {
        int v[8];
        int s = 0;
#pragma unroll
        for (int j = 0; j < 8; j++) {
            int idx = t * 8 + j;
            v[j] = (idx < NBIN) ? cnt_ar[idx] : 0;
            s += v[j];
        }
        sh[t] = s;
        __syncthreads();
        for (int off = 1; off < 1024; off <<= 1) {
            int x = (t >= off) ? sh[t - off] : 0;
            __syncthreads();
            sh[t] += x;
            __syncthreads();
        }
        int run = sh[t] - s;  // exclusive prefix of this thread's chunk
#pragma unroll
        for (int j = 0; j < 8; j++) {
            int idx = t * 8 + j;
            if (idx < NBIN) rp_ar[idx] = run;
            run += v[j];
        }
        if (t == 1023) rp_ar[NBIN] = sh[1023];
        __syncthreads();   // drains global writes (vmcnt) before cross-thread read
        if (t < NC2A) ccur[t] = rp_ar[t * 128];
    } else {
        int v = (t < NBKT) ? bcnt[t] : 0;
        sh[t] = v;
        __syncthreads();
        for (int off = 1; off < 1024; off <<= 1) {
            int x = (t >= off) ? sh[t - off] : 0;
            __syncthreads();
            sh[t] += x;
            __syncthreads();
        }
        if (t == 0) { brp[0] = 0; bcur[0] = 0; }
        if (t < NBKT) {
            brp[t + 1] = sh[t];
            if (t + 1 < NBKT) bcur[t + 1] = sh[t];
        }
    }
}

// ---------------- phase 3: pass A — coarse scatter (block-private contiguous runs) ----
// blocks [0,256): c2a -> tmp1 bucketed by bin>>7 (63 buckets), payload bin<<17|src
// blocks [256,512): a2c -> tmp2 bucketed by dst>>10 (98 buckets), payload (dst&1023)<<10|src
// Per-block per-bucket runs ~400B, block-private -> no cross-XCD line sharing,
// write amplification ~1 (was 7x with direct 4B scatter into 8000/782 bins).
__global__ __launch_bounds__(1024) void scatter_coarse(const int* __restrict__ c2a_src,
                                                       const int* __restrict__ c2a_dst,
                                                       const int* __restrict__ a2c_src,
                                                       const int* __restrict__ a2c_dst, int E,
                                                       int* __restrict__ ccur,
                                                       int* __restrict__ tmp1,
                                                       int* __restrict__ bcur,
                                                       int* __restrict__ tmp2) {
    __shared__ int h[NBKT], base[NBKT];
    int tid = threadIdx.x;
    if (blockIdx.x < 256) {
        int chunk = (E + 255) / 256;
        int e0 = blockIdx.x * chunk;
        int e1 = min(E, e0 + chunk);
        for (int i = tid; i < NC2A; i += 1024) h[i] = 0;
        __syncthreads();
        for (int e = e0 + tid; e < e1; e += 1024) {
            int s = c2a_src[e];
            int bin = c2a_dst[e] * NRNG + (int)__umulhi((unsigned)s, RMAGIC);
            atomicAdd(&h[bin >> 7], 1);
        }
        __syncthreads();
        for (int i = tid; i < NC2A; i += 1024) {
            int c = h[i];
            base[i] = c ? atomicAdd(&ccur[i], c) : 0;
        }
        __syncthreads();
        for (int e = e0 + tid; e < e1; e += 1024) {
            int s = c2a_src[e];
            int bin = c2a_dst[e] * NRNG + (int)__umulhi((unsigned)s, RMAGIC);
            int pos = atomicAdd(&base[bin >> 7], 1);
            tmp1[pos] = (bin << 17) | s;
        }
    } else {
        int bid = blockIdx.x - 256;
        int chunk = (E + 255) / 256;
        int e0 = bid * chunk;
        int e1 = min(E, e0 + chunk);
        for (int i = tid; i < NBKT; i += 1024) h[i] = 0;
        __syncthreads();
        for (int e = e0 + tid; e < e1; e += 1024) atomicAdd(&h[a2c_dst[e] >> 10], 1);
        __syncthreads();
        for (int i = tid; i < NBKT; i += 1024) {
            int c = h[i];
            base[i] = c ? atomicAdd(&bcur[i], c) : 0;
        }
        __syncthreads();
        for (int e = e0 + tid; e < e1; e += 1024) {
            int d = a2c_dst[e];
            int pos = atomicAdd(&base[d >> 10], 1);
            tmp2[pos] = ((d & 1023) << 10) | a2c_src[e];
        }
    }
}

// ---------------- phase 4: pass B — refine within coarse buckets ----------------
// blocks [0,63): c2a bucket c -> col_c2a via LDS cursors seeded from rp_ar (1 pass).
// blocks [63,161): a2c bucket b -> rp_c + col_a2c (in-block 1024-client histo+scan).
// All writes land in the block's contiguous L2-resident output region.
__global__ __launch_bounds__(1024) void refine(const int* __restrict__ rp_ar,
                                               const int* __restrict__ tmp1,
                                               int* __restrict__ col_c2a,
                                               const int* __restrict__ brp,
                                               const int* __restrict__ tmp2,
                                               int* __restrict__ rp_c,
                                               int* __restrict__ col_a2c) {
    int tid = threadIdx.x;
    if (blockIdx.x < NC2A) {
        __shared__ int lcur[128];
        int c = blockIdx.x;
        int b0 = c * 128;
        int nb = min(128, NBIN - b0);
        if (tid < nb) lcur[tid] = rp_ar[b0 + tid];
        int beg = rp_ar[b0];
        int end = rp_ar[min(b0 + 128, NBIN)];
        __syncthreads();
        for (int e = beg + tid; e < end; e += 1024) {
            int v = tmp1[e];
            int pos = atomicAdd(&lcur[(v >> 17) - b0], 1);
            col_c2a[pos] = v & 0x1FFFF;
        }
    } else {
        __shared__ int h2[1024], cur2[1024];
        int b = blockIdx.x - NC2A;
        int beg = brp[b], end = brp[b + 1];
        h2[tid] = 0;
        __syncthreads();
        for (int e = beg + tid; e < end; e += 1024) atomicAdd(&h2[tmp2[e] >> 10], 1);
        __syncthreads();
        cur2[tid] = h2[tid];
        __syncthreads();
        for (int off = 1; off < 1024; off <<= 1) {
            int x = (tid >= off) ? cur2[tid - off] : 0;
            __syncthreads();
            cur2[tid] += x;
            __syncthreads();
        }
        int start = beg + cur2[tid] - h2[tid];
        int c = b * 1024 + tid;
        if (c < NCLI) rp_c[c] = start;
        cur2[tid] = start;
        if (b == NBKT - 1 && tid == 0) rp_c[NCLI] = end;
        __syncthreads();
        for (int e = beg + tid; e < end; e += 1024) {
            int p = tmp2[e];
            int pos = atomicAdd(&cur2[p >> 10], 1);
            col_a2c[pos] = p & 1023;
        }
    }
}

// ---------------- layer kernels ----------------

// XCD-sliced mean gather (unchanged).
__global__ __launch_bounds__(512) void gather_mean(const unsigned* __restrict__ tbl,
                                                   const int* __restrict__ rp_ar,
                                                   const int* __restrict__ col,
                                                   float* __restrict__ psum) {
    __shared__ float part[4][8][D];   // 16 KB
    int quad = blockIdx.x >> 3, r = blockIdx.x & 7;
    int tid = threadIdx.x;
    int a = tid >> 7;            // local agg 0..3
    int sub = (tid >> 4) & 7;    // reader 0..7
    int sl = tid & 15;           // lane in reader
    const uint4* tbl4 = (const uint4*)tbl;
    int agg = quad * 4 + a;
    int bin = agg * NRNG + r;
    int beg = rp_ar[bin], end = rp_ar[bin + 1];
    float f0 = 0, f1 = 0, f2 = 0, f3 = 0, f4 = 0, f5 = 0, f6 = 0, f7 = 0;
    int e = beg + sub;
    for (; e + 8 < end; e += 16) {   // 2 edges in flight per reader
        int s0 = col[e];
        int s1 = col[e + 8];
        uint4 v0 = tbl4[(s0 << 4) + sl];
        uint4 v1 = tbl4[(s1 << 4) + sl];
        f0 += bf_lo(v0.x); f1 += bf_hi(v0.x); f2 += bf_lo(v0.y); f3 += bf_hi(v0.y);
        f4 += bf_lo(v0.z); f5 += bf_hi(v0.z); f6 += bf_lo(v0.w); f7 += bf_hi(v0.w);
        f0 += bf_lo(v1.x); f1 += bf_hi(v1.x); f2 += bf_lo(v1.y); f3 += bf_hi(v1.y);
        f4 += bf_lo(v1.z); f5 += bf_hi(v1.z); f6 += bf_lo(v1.w); f7 += bf_hi(v1.w);
    }
    if (e < end) {
        int s0 = col[e];
        uint4 v0 = tbl4[(s0 << 4) + sl];
        f0 += bf_lo(v0.x); f1 += bf_hi(v0.x); f2 += bf_lo(v0.y); f3 += bf_hi(v0.y);
        f4 += bf_lo(v0.z); f5 += bf_hi(v0.z); f6 += bf_lo(v0.w); f7 += bf_hi(v0.w);
    }
    float* pr = &part[a][sub][sl * 8];
    pr[0] = f0; pr[1] = f1; pr[2] = f2; pr[3] = f3;
    pr[4] = f4; pr[5] = f5; pr[6] = f6; pr[7] = f7;
    __syncthreads();
    int c = tid & 127;
    float s = 0.f;
#pragma unroll
    for (int g = 0; g < 8; g++) s += part[a][g][c];
    psum[((size_t)agg * NRNG + r) * D + c] = s;
}

// combine partials -> mean; then ya = xa@Wl_a2c (bf16), xa_new = leaky(mean@Wl_c2a + xa@Wr_c2a + b)
__global__ __launch_bounds__(128) void combine_agg(const float* __restrict__ psum,
                                                   const int* __restrict__ rp_ar,
                                                   const float* xa_old,
                                                   const float* __restrict__ Wl_a2c,
                                                   const float* __restrict__ Wl_c2a,
                                                   const float* __restrict__ Wr_c2a,
                                                   const float* __restrict__ b_c2a,
                                                   unsigned short* __restrict__ ya_bf,
                                                   float* xa_out) {
    __shared__ float mr[D], xr[D];
    int i = blockIdx.x, j = threadIdx.x;
    const float* pr = psum + (size_t)i * NRNG * D + j;
    float s = 0.f;
#pragma unroll
    for (int r = 0; r < NRNG; r++) s += pr[r * D];
    int deg = rp_ar[i * NRNG + NRNG] - rp_ar[i * NRNG];
    mr[j] = s / fmaxf((float)deg, 1.f);
    xr[j] = xa_old[i * D + j];
    __syncthreads();
    float accy = 0.f, accn = b_c2a[j];
#pragma unroll 4
    for (int k = 0; k < D; k++) {
        accy += xr[k] * Wl_a2c[k * D + j];
        accn += mr[k] * Wl_c2a[k * D + j] + xr[k] * Wr_c2a[k * D + j];
    }
    ya_bf[i * D + j] = (unsigned short)bf16_rn(accy);
    xa_out[i * D + j] = leaky(accn);
}

// FUSED gemm+agg — EXACT R4 version (empirical optimum of this phase: 89.5us).
// Col slice prefetched to LDS before A-frag loads; agg via four 16-lane groups
// per wave, lane q owns dims 8q..8q+7 (uint4 per edge).
#define ACC8(vv) do { \
    s0 += bf_lo(vv.x); s1 += bf_hi(vv.x); s2 += bf_lo(vv.y); s3 += bf_hi(vv.y); \
    s4 += bf_lo(vv.z); s5 += bf_hi(vv.z); s6 += bf_lo(vv.w); s7 += bf_hi(vv.w); } while (0)

#define GBLOCK(SRC) do { \
    int r0 = (SRC)[0], r1 = (SRC)[1], r2 = (SRC)[2], r3 = (SRC)[3]; \
    int r4 = (SRC)[4], r5 = (SRC)[5], r6 = (SRC)[6], r7 = (SRC)[7]; \
    uint4 v0 = ya4[(r0 << 4) + q]; uint4 v1 = ya4[(r1 << 4) + q]; \
    uint4 v2 = ya4[(r2 << 4) + q]; uint4 v3 = ya4[(r3 << 4) + q]; \
    uint4 v4 = ya4[(r4 << 4) + q]; uint4 v5 = ya4[(r5 << 4) + q]; \
    uint4 v6 = ya4[(r6 << 4) + q]; uint4 v7 = ya4[(r7 << 4) + q]; \
    ACC8(v0); ACC8(v1); ACC8(v2); ACC8(v3); \
    ACC8(v4); ACC8(v5); ACC8(v6); ACC8(v7); } while (0)

#define GTAIL(SRC) do { \
    int rr = (SRC)[0]; \
    uint4 v = ya4[(rr << 4) + q]; \
    ACC8(v); } while (0)

template <int LAST>
__global__ __launch_bounds__(256) void gemm_agg(const unsigned short* __restrict__ Ahi,
                                                const unsigned short* __restrict__ Alo,
                                                const unsigned short* __restrict__ Wt,
                                                const float* __restrict__ bias,
                                                const unsigned* __restrict__ ya,
                                                const int* __restrict__ rowptr,
                                                const int* __restrict__ col,
                                                unsigned* __restrict__ xhi,
                                                unsigned* __restrict__ xlo,
                                                const float* __restrict__ Wlin,
                                                const float* __restrict__ blin,
                                                float* __restrict__ out, int E) {
    __shared__ float smem[32][D];   // 16 KB tile of gemm output
    __shared__ int lcol[CAP_E];     // 6 KB col slice
    int tid = threadIdx.x;
    int wave = tid >> 6, lane = tid & 63;
    int cl = lane & 31, kh = lane >> 5;
    int n0 = wave * 32;
    int m0 = blockIdx.x * 32;
    int blkBeg = rowptr[m0], blkEnd = rowptr[m0 + 32];
    int nE = blkEnd - blkBeg;
    bool inlds = (nE <= CAP_E);
    // issue col-slice prefetch FIRST: its HBM latency hides under B/A loads + MFMA
    int pv[6];
#pragma unroll
    for (int k = 0; k < 6; k++) pv[k] = col[min(blkBeg + tid + k * 256, E - 1)];
    const unsigned short* Wlo_ = Wt + D * D;
    const unsigned short* wbh = Wt + (size_t)(n0 + cl) * D + kh * 8;
    const unsigned short* wbl = Wlo_ + (size_t)(n0 + cl) * D + kh * 8;
    bf16x8 bhi[8], blo[8];
#pragma unroll
    for (int kc = 0; kc < 8; kc++) {
        bhi[kc] = *(const bf16x8*)(wbh + kc * 16);
        blo[kc] = *(const bf16x8*)(wbl + kc * 16);
    }
    float bv = bias[n0 + cl];
    {
        const unsigned short* ar = Ahi + (size_t)(m0 + cl) * D + kh * 8;
        const unsigned short* al = Alo + (size_t)(m0 + cl) * D + kh * 8;
        bf16x8 ahi[8], alo[8];
#pragma unroll
        for (int kc = 0; kc < 8; kc++) {
            ahi[kc] = *(const bf16x8*)(ar + kc * 16);
            alo[kc] = *(const bf16x8*)(al + kc * 16);
        }
        // stash col slice to LDS (waits only on the pv loads; A loads stay in flight)
        if (inlds) {
#pragma unroll
            for (int k = 0; k < 6; k++) lcol[tid + k * 256] = pv[k];
        }
        f32x16 acc;
#pragma unroll
        for (int q = 0; q < 16; q++) acc[q] = bv;
#pragma unroll
        for (int kc = 0; kc < 8; kc++) {
            acc = __builtin_amdgcn_mfma_f32_32x32x16_bf16(ahi[kc], bhi[kc], acc, 0, 0, 0);
            acc = __builtin_amdgcn_mfma_f32_32x32x16_bf16(alo[kc], bhi[kc], acc, 0, 0, 0);
            acc = __builtin_amdgcn_mfma_f32_32x32x16_bf16(ahi[kc], blo[kc], acc, 0, 0, 0);
        }
#pragma unroll
        for (int reg = 0; reg < 16; reg++) {
            int row = (reg & 3) + 8 * (reg >> 2) + 4 * kh;
            smem[row][n0 + cl] = acc[reg];   // 2 lanes/bank max -> conflict-free
        }
    }
    __syncthreads();
    // agg: 4 groups of 16 lanes per wave; group g owns client wave*8 + pass*4 + g.
    // Lane q covers dims 8q..8q+7 (one uint4 of the 64-word ya row).
    const uint4* ya4 = (const uint4*)ya;
    int g = lane >> 4, q = lane & 15;
#pragma unroll
    for (int pass = 0; pass < 2; pass++) {
        int c_local = wave * 8 + pass * 4 + g;
        int gid = m0 + c_local;
        int beg = rowptr[gid], end = rowptr[gid + 1];
        int len = end - beg;
        float s0 = 0, s1 = 0, s2 = 0, s3 = 0, s4 = 0, s5 = 0, s6 = 0, s7 = 0;
        if (inlds) {
            const int* src = lcol + (beg - blkBeg);
            int j = 0;
            for (; j + 8 <= len; j += 8) GBLOCK(src + j);
            for (; j < len; j++) GTAIL(src + j);
        } else {
            const int* src = col + beg;
            int j = 0;
            for (; j + 8 <= len; j += 8) GBLOCK(src + j);
            for (; j < len; j++) GTAIL(src + j);
        }
        float inv = 1.f / fmaxf((float)len, 1.f);
        float4 y0 = *(const float4*)&smem[c_local][8 * q];
        float4 y1 = *(const float4*)&smem[c_local][8 * q + 4];
        float r0 = leaky(y0.x + s0 * inv);
        float r1 = leaky(y0.y + s1 * inv);
        float r2 = leaky(y0.z + s2 * inv);
        float r3 = leaky(y0.w + s3 * inv);
        float r4 = leaky(y1.x + s4 * inv);
        float r5 = leaky(y1.y + s5 * inv);
        float r6 = leaky(y1.z + s6 * inv);
        float r7 = leaky(y1.w + s7 * inv);
        if (LAST) {
            float4 w0 = *(const float4*)&Wlin[8 * q];
            float4 w1 = *(const float4*)&Wlin[8 * q + 4];
            float v = r0 * w0.x + r1 * w0.y + r2 * w0.z + r3 * w0.w +
                      r4 * w1.x + r5 * w1.y + r6 * w1.z + r7 * w1.w;
#pragma unroll
            for (int off = 8; off > 0; off >>= 1) v += __shfl_down(v, off, 16);
            if (q == 0) out[gid] = v + blin[0];
        } else {
            unsigned h0 = bf16_rn(r0), h1 = bf16_rn(r1), h2 = bf16_rn(r2), h3 = bf16_rn(r3);
            unsigned h4 = bf16_rn(r4), h5 = bf16_rn(r5), h6 = bf16_rn(r6), h7 = bf16_rn(r7);
            uint4 hi, lo;
            hi.x = h0 | (h1 << 16); hi.y = h2 | (h3 << 16);
            hi.z = h4 | (h5 << 16); hi.w = h6 | (h7 << 16);
            lo.x = pack_bf2(r0 - bf_val(h0), r1 - bf_val(h1));
            lo.y = pack_bf2(r2 - bf_val(h2), r3 - bf_val(h3));
            lo.z = pack_bf2(r4 - bf_val(h4), r5 - bf_val(h5));
            lo.w = pack_bf2(r6 - bf_val(h6), r7 - bf_val(h7));
            ((uint4*)xhi)[(gid << 4) + q] = hi;
            ((uint4*)xlo)[(gid << 4) + q] = lo;
        }
    }
}

extern "C" void kernel_launch(void* const* d_in, const int* in_sizes, int n_in,
                              void* d_out, int out_size, void* d_ws, size_t ws_size,
                              hipStream_t stream) {
    const float* x_clients = (const float*)d_in[0];
    const float* x_agg     = (const float*)d_in[1];
    const int*   c2a_src   = (const int*)d_in[2];
    const int*   c2a_dst   = (const int*)d_in[3];
    const int*   a2c_src   = (const int*)d_in[4];
    const int*   a2c_dst   = (const int*)d_in[5];
    const float* Wl_c2a    = (const float*)d_in[6];
    const float* Wr_c2a    = (const float*)d_in[7];
    const float* b_c2a     = (const float*)d_in[8];
    const float* Wl_a2c    = (const float*)d_in[9];
    const float* Wr_a2c    = (const float*)d_in[10];
    const float* b_a2c     = (const float*)d_in[11];
    const float* W_lin     = (const float*)d_in[12];
    const float* b_lin     = (const float*)d_in[13];
    float* out = (float*)d_out;
    const int E = in_sizes[2];

    char* p = (char*)d_ws;
    auto alloc = [&](size_t bytes) {
        char* r = p;
        p += (bytes + 255) & ~(size_t)255;
        return r;
    };
    float*    Yb    = (float*)alloc(sizeof(float) * NCLI * D);         // tmp1/tmp2 scratch only
    unsigned* xc_hi = (unsigned*)alloc(sizeof(unsigned) * NCLI * 64);  // bf16 hi (also gather tbl)
    unsigned* xc_lo = (unsigned*)alloc(sizeof(unsigned) * NCLI * 64);  // bf16 lo
    float*    xa    = (float*)alloc(sizeof(float) * NAGG * D);
    unsigned short* ya_bf = (unsigned short*)alloc(sizeof(unsigned short) * NAGG * D);
    unsigned short* Wt = (unsigned short*)alloc(sizeof(unsigned short) * NLAYER * 2 * D * D);
    float* psum  = (float*)alloc(sizeof(float) * NAGG * NRNG * D);     // 4 MB gather partials
    int* cnt_ar = (int*)alloc(sizeof(int) * (NBIN + NBKT));  // cnt_ar[0..7999] + bcnt
    int* bcnt  = cnt_ar + NBIN;
    int* rp_ar = (int*)alloc(sizeof(int) * (NBIN + 1));
    int* brp   = (int*)alloc(sizeof(int) * (NBKT + 1));
    int* bcur  = (int*)alloc(sizeof(int) * NBKT);
    int* ccur  = (int*)alloc(sizeof(int) * NC2A);
    int* rp_c  = (int*)alloc(sizeof(int) * (NCLI + 1));
    int* col_c2a = (int*)alloc(sizeof(int) * E);
    int* col_a2c = (int*)alloc(sizeof(int) * E);
    // tmp1/tmp2 alias Yb (12.8 MB needed, 51.2 MB available); lifetime ends before layers
    int* tmp1 = (int*)Yb;
    int* tmp2 = tmp1 + E;

    hipMemsetAsync(cnt_ar, 0, sizeof(int) * (NBIN + NBKT), stream);

    prep<<<NHIST + NCVTX + NCVTW, 256, 0, stream>>>(c2a_src, c2a_dst, a2c_dst, E, cnt_ar, bcnt,
                                                    (const float4*)x_clients,
                                                    (uint2*)xc_hi, (uint2*)xc_lo,
                                                    Wr_a2c, Wt);
    scan_both<<<2, 1024, 0, stream>>>(cnt_ar, rp_ar, bcnt, brp, bcur, ccur);
    scatter_coarse<<<512, 1024, 0, stream>>>(c2a_src, c2a_dst, a2c_src, a2c_dst, E,
                                             ccur, tmp1, bcur, tmp2);
    refine<<<NC2A + NBKT, 1024, 0, stream>>>(rp_ar, tmp1, col_c2a, brp, tmp2, rp_c, col_a2c);

    const float* xa_old = x_agg;
    for (int l = 0; l < NLAYER; l++) {
        gather_mean<<<(NAGG / 4) * NRNG, 512, 0, stream>>>(xc_hi, rp_ar, col_c2a, psum);
        combine_agg<<<NAGG, 128, 0, stream>>>(psum, rp_ar, xa_old,
                                              Wl_a2c + l * D * D, Wl_c2a + l * D * D,
                                              Wr_c2a + l * D * D, b_c2a + l * D, ya_bf, xa);
        if (l < NLAYER - 1) {
            gemm_agg<0><<<NROWT, 256, 0, stream>>>(
                (const unsigned short*)xc_hi, (const unsigned short*)xc_lo,
                Wt + l * 2 * D * D, b_a2c + l * D, (const unsigned*)ya_bf, rp_c, col_a2c,
                xc_hi, xc_lo, nullptr, nullptr, nullptr, E);
        } else {
            gemm_agg<1><<<NROWT, 256, 0, stream>>>(
                (const unsigned short*)xc_hi, (const unsigned short*)xc_lo,
                Wt + l * 2 * D * D, b_a2c + l * D, (const unsigned*)ya_bf, rp_c, col_a2c,
                nullptr, nullptr, W_lin, b_lin, out, E);
        }
        xa_old = xa;
    }
}

// Round 9
// 555.045 us; speedup vs baseline: 1.5525x; 1.0774x over previous
//
#include <hip/hip_runtime.h>

#define D      128
#define NCLI   100000
#define NAGG   1000
#define NLAYER 3
#define NBKT   98    // coarse a2c buckets (dst>>10), 98*1024 >= 100000
#define NC2A   63    // coarse c2a buckets (bin>>7), 63*128 >= 8000
#define NRNG   8     // src ranges for c2a CSR (12500 clients each, 3.2 MB slice/XCD-L2)
#define NBIN   (NAGG * NRNG)   // 8000
#define RMAGIC 343598u         // ceil(2^32/12500): r = umulhi(src, RMAGIC), exact for src<100000
#define NHIST  512
#define NCVTX  (NCLI * D / 4 / 256)   // 12500
#define NCVTW  ((NLAYER * D * D + 255) / 256)  // 192
#define NROWT  (NCLI / 32)            // 3125 row-tiles (exact)
#define CAP_E  1536   // per-block col prefetch capacity (mean 512; huge headroom)

typedef short bf16x8 __attribute__((ext_vector_type(8)));
typedef float f32x16 __attribute__((ext_vector_type(16)));

static __device__ __forceinline__ float leaky(float x) { return x >= 0.f ? x : 0.1f * x; }

// ---- bf16 pack/unpack (RNE) ----
static __device__ __forceinline__ unsigned bf16_rn(float f) {
    unsigned u = __float_as_uint(f);
    return (u + 0x7fffu + ((u >> 16) & 1u)) >> 16;
}
static __device__ __forceinline__ float bf_val(unsigned h) { return __uint_as_float(h << 16); }
static __device__ __forceinline__ unsigned pack_bf2(float lo, float hi) {
    return bf16_rn(lo) | (bf16_rn(hi) << 16);
}
static __device__ __forceinline__ float bf_lo(unsigned v) { return __uint_as_float(v << 16); }
static __device__ __forceinline__ float bf_hi(unsigned v) { return __uint_as_float(v & 0xffff0000u); }

// ---------------- phase 1: hist + feature/weight cvt, one launch ----------------
__global__ __launch_bounds__(256) void prep(const int* __restrict__ c2a_src,
                                            const int* __restrict__ c2a_dst,
                                            const int* __restrict__ a2c_dst, int E,
                                            int* __restrict__ cnt_ar, int* __restrict__ bcnt,
                                            const float4* __restrict__ X4,
                                            uint2* __restrict__ xhi, uint2* __restrict__ xlo,
                                            const float* __restrict__ W,
                                            unsigned short* __restrict__ Wt) {
    __shared__ int h[NBIN + NBKT];   // 32.4 KB
    int bid = blockIdx.x;
    if (bid < NHIST) {
        for (int i = threadIdx.x; i < NBIN + NBKT; i += 256) h[i] = 0;
        __syncthreads();
        int stride = NHIST * 256;
        for (int e = bid * 256 + threadIdx.x; e < E; e += stride) {
            int s = c2a_src[e];
            int bin = c2a_dst[e] * NRNG + (int)__umulhi((unsigned)s, RMAGIC);
            atomicAdd(&h[bin], 1);
            atomicAdd(&h[NBIN + (a2c_dst[e] >> 10)], 1);
        }
        __syncthreads();
        for (int i = threadIdx.x; i < NBIN; i += 256)
            if (h[i]) atomicAdd(&cnt_ar[i], h[i]);
        for (int i = threadIdx.x; i < NBKT; i += 256)
            if (h[NBIN + i]) atomicAdd(&bcnt[i], h[NBIN + i]);
    } else if (bid < NHIST + NCVTX) {
        int t = (bid - NHIST) * 256 + threadIdx.x;
        float4 f = X4[t];
        unsigned h0 = bf16_rn(f.x), h1 = bf16_rn(f.y), h2 = bf16_rn(f.z), h3 = bf16_rn(f.w);
        xhi[t] = make_uint2(h0 | (h1 << 16), h2 | (h3 << 16));
        xlo[t] = make_uint2(pack_bf2(f.x - bf_val(h0), f.y - bf_val(h1)),
                            pack_bf2(f.z - bf_val(h2), f.w - bf_val(h3)));
    } else {
        int idx = (bid - NHIST - NCVTX) * 256 + threadIdx.x;
        if (idx >= NLAYER * D * D) return;
        int layer = idx >> 14, rem = idx & (D * D - 1);
        int k = rem >> 7, n = rem & 127;
        float w = W[layer * D * D + k * D + n];
        unsigned hh = bf16_rn(w);
        unsigned short* base = Wt + layer * 2 * D * D;
        base[n * D + k] = (unsigned short)hh;
        base[D * D + n * D + k] = (unsigned short)bf16_rn(w - bf_val(hh));
    }
}

// ---------------- phase 2: scans ----------------
__global__ void scan_both(const int* __restrict__ cnt_ar, int* __restrict__ rp_ar,
                          const int* __restrict__ bcnt,
                          int* __restrict__ brp, int* __restrict__ bcur,
                          int* __restrict__ ccur) {
    __shared__ int sh[1024];
    int t = threadIdx.x;
    if (blockIdx.x == 0) {
        int v[8];
        int s = 0;
#pragma unroll
        for (int j = 0; j < 8; j++) {
            int idx = t * 8 + j;
            v[j] = (idx < NBIN) ? cnt_ar[idx] : 0;
            s += v[j];
        }
        sh[t] = s;
        __syncthreads();
        for (int off = 1; off < 1024; off <<= 1) {
            int x = (t >= off) ? sh[t - off] : 0;
            __syncthreads();
            sh[t] += x;
            __syncthreads();
        }
        int run = sh[t] - s;  // exclusive prefix of this thread's chunk
#pragma unroll
        for (int j = 0; j < 8; j++) {
            int idx = t * 8 + j;
            if (idx < NBIN) rp_ar[idx] = run;
            run += v[j];
        }
        if (t == 1023) rp_ar[NBIN] = sh[1023];
        __syncthreads();   // drains global writes before cross-thread read
        if (t < NC2A) ccur[t] = rp_ar[t * 128];
    } else {
        int v = (t < NBKT) ? bcnt[t] : 0;
        sh[t] = v;
        __syncthreads();
        for (int off = 1; off < 1024; off <<= 1) {
            int x = (t >= off) ? sh[t - off] : 0;
            __syncthreads();
            sh[t] += x;
            __syncthreads();
        }
        if (t == 0) { brp[0] = 0; bcur[0] = 0; }
        if (t < NBKT) {
            brp[t + 1] = sh[t];
            if (t + 1 < NBKT) bcur[t + 1] = sh[t];
        }
    }
}

// ---------------- phase 3: pass A — coarse scatter (block-private contiguous runs) ----
__global__ __launch_bounds__(1024) void scatter_coarse(const int* __restrict__ c2a_src,
                                                       const int* __restrict__ c2a_dst,
                                                       const int* __restrict__ a2c_src,
                                                       const int* __restrict__ a2c_dst, int E,
                                                       int* __restrict__ ccur,
                                                       int* __restrict__ tmp1,
                                                       int* __restrict__ bcur,
                                                       int* __restrict__ tmp2) {
    __shared__ int h[NBKT], base[NBKT];
    int tid = threadIdx.x;
    if (blockIdx.x < 256) {
        int chunk = (E + 255) / 256;
        int e0 = blockIdx.x * chunk;
        int e1 = min(E, e0 + chunk);
        for (int i = tid; i < NC2A; i += 1024) h[i] = 0;
        __syncthreads();
        for (int e = e0 + tid; e < e1; e += 1024) {
            int s = c2a_src[e];
            int bin = c2a_dst[e] * NRNG + (int)__umulhi((unsigned)s, RMAGIC);
            atomicAdd(&h[bin >> 7], 1);
        }
        __syncthreads();
        for (int i = tid; i < NC2A; i += 1024) {
            int c = h[i];
            base[i] = c ? atomicAdd(&ccur[i], c) : 0;
        }
        __syncthreads();
        for (int e = e0 + tid; e < e1; e += 1024) {
            int s = c2a_src[e];
            int bin = c2a_dst[e] * NRNG + (int)__umulhi((unsigned)s, RMAGIC);
            int pos = atomicAdd(&base[bin >> 7], 1);
            tmp1[pos] = (bin << 17) | s;
        }
    } else {
        int bid = blockIdx.x - 256;
        int chunk = (E + 255) / 256;
        int e0 = bid * chunk;
        int e1 = min(E, e0 + chunk);
        for (int i = tid; i < NBKT; i += 1024) h[i] = 0;
        __syncthreads();
        for (int e = e0 + tid; e < e1; e += 1024) atomicAdd(&h[a2c_dst[e] >> 10], 1);
        __syncthreads();
        for (int i = tid; i < NBKT; i += 1024) {
            int c = h[i];
            base[i] = c ? atomicAdd(&bcur[i], c) : 0;
        }
        __syncthreads();
        for (int e = e0 + tid; e < e1; e += 1024) {
            int d = a2c_dst[e];
            int pos = atomicAdd(&base[d >> 10], 1);
            tmp2[pos] = ((d & 1023) << 10) | a2c_src[e];
        }
    }
}

// ---------------- phase 4: pass B — refine within coarse buckets ----------------
__global__ __launch_bounds__(1024) void refine(const int* __restrict__ rp_ar,
                                               const int* __restrict__ tmp1,
                                               int* __restrict__ col_c2a,
                                               const int* __restrict__ brp,
                                               const int* __restrict__ tmp2,
                                               int* __restrict__ rp_c,
                                               int* __restrict__ col_a2c) {
    int tid = threadIdx.x;
    if (blockIdx.x < NC2A) {
        __shared__ int lcur[128];
        int c = blockIdx.x;
        int b0 = c * 128;
        int nb = min(128, NBIN - b0);
        if (tid < nb) lcur[tid] = rp_ar[b0 + tid];
        int beg = rp_ar[b0];
        int end = rp_ar[min(b0 + 128, NBIN)];
        __syncthreads();
        for (int e = beg + tid; e < end; e += 1024) {
            int v = tmp1[e];
            int pos = atomicAdd(&lcur[(v >> 17) - b0], 1);
            col_c2a[pos] = v & 0x1FFFF;
        }
    } else {
        __shared__ int h2[1024], cur2[1024];
        int b = blockIdx.x - NC2A;
        int beg = brp[b], end = brp[b + 1];
        h2[tid] = 0;
        __syncthreads();
        for (int e = beg + tid; e < end; e += 1024) atomicAdd(&h2[tmp2[e] >> 10], 1);
        __syncthreads();
        cur2[tid] = h2[tid];
        __syncthreads();
        for (int off = 1; off < 1024; off <<= 1) {
            int x = (tid >= off) ? cur2[tid - off] : 0;
            __syncthreads();
            cur2[tid] += x;
            __syncthreads();
        }
        int start = beg + cur2[tid] - h2[tid];
        int c = b * 1024 + tid;
        if (c < NCLI) rp_c[c] = start;
        cur2[tid] = start;
        if (b == NBKT - 1 && tid == 0) rp_c[NCLI] = end;
        __syncthreads();
        for (int e = beg + tid; e < end; e += 1024) {
            int p = tmp2[e];
            int pos = atomicAdd(&cur2[p >> 10], 1);
            col_a2c[pos] = p & 1023;
        }
    }
}

// ---------------- layer kernels ----------------

// XCD-sliced mean gather (unchanged). NOT launched for the last layer (xa dead).
__global__ __launch_bounds__(512) void gather_mean(const unsigned* __restrict__ tbl,
                                                   const int* __restrict__ rp_ar,
                                                   const int* __restrict__ col,
                                                   float* __restrict__ psum) {
    __shared__ float part[4][8][D];   // 16 KB
    int quad = blockIdx.x >> 3, r = blockIdx.x & 7;
    int tid = threadIdx.x;
    int a = tid >> 7;            // local agg 0..3
    int sub = (tid >> 4) & 7;    // reader 0..7
    int sl = tid & 15;           // lane in reader
    const uint4* tbl4 = (const uint4*)tbl;
    int agg = quad * 4 + a;
    int bin = agg * NRNG + r;
    int beg = rp_ar[bin], end = rp_ar[bin + 1];
    float f0 = 0, f1 = 0, f2 = 0, f3 = 0, f4 = 0, f5 = 0, f6 = 0, f7 = 0;
    int e = beg + sub;
    for (; e + 8 < end; e += 16) {   // 2 edges in flight per reader
        int s0 = col[e];
        int s1 = col[e + 8];
        uint4 v0 = tbl4[(s0 << 4) + sl];
        uint4 v1 = tbl4[(s1 << 4) + sl];
        f0 += bf_lo(v0.x); f1 += bf_hi(v0.x); f2 += bf_lo(v0.y); f3 += bf_hi(v0.y);
        f4 += bf_lo(v0.z); f5 += bf_hi(v0.z); f6 += bf_lo(v0.w); f7 += bf_hi(v0.w);
        f0 += bf_lo(v1.x); f1 += bf_hi(v1.x); f2 += bf_lo(v1.y); f3 += bf_hi(v1.y);
        f4 += bf_lo(v1.z); f5 += bf_hi(v1.z); f6 += bf_lo(v1.w); f7 += bf_hi(v1.w);
    }
    if (e < end) {
        int s0 = col[e];
        uint4 v0 = tbl4[(s0 << 4) + sl];
        f0 += bf_lo(v0.x); f1 += bf_hi(v0.x); f2 += bf_lo(v0.y); f3 += bf_hi(v0.y);
        f4 += bf_lo(v0.z); f5 += bf_hi(v0.z); f6 += bf_lo(v0.w); f7 += bf_hi(v0.w);
    }
    float* pr = &part[a][sub][sl * 8];
    pr[0] = f0; pr[1] = f1; pr[2] = f2; pr[3] = f3;
    pr[4] = f4; pr[5] = f5; pr[6] = f6; pr[7] = f7;
    __syncthreads();
    int c = tid & 127;
    float s = 0.f;
#pragma unroll
    for (int g = 0; g < 8; g++) s += part[a][g][c];
    psum[((size_t)agg * NRNG + r) * D + c] = s;
}

// combine partials -> mean; ya = xa@Wl_a2c (bf16); xa_new = leaky(...).
// LAST=1: final layer's xa is DEAD (reference output only uses xc) -> compute only ya.
template <int LAST>
__global__ __launch_bounds__(128) void combine_agg(const float* __restrict__ psum,
                                                   const int* __restrict__ rp_ar,
                                                   const float* xa_old,
                                                   const float* __restrict__ Wl_a2c,
                                                   const float* __restrict__ Wl_c2a,
                                                   const float* __restrict__ Wr_c2a,
                                                   const float* __restrict__ b_c2a,
                                                   unsigned short* __restrict__ ya_bf,
                                                   float* xa_out) {
    __shared__ float mr[D], xr[D];
    int i = blockIdx.x, j = threadIdx.x;
    if (LAST) {
        xr[j] = xa_old[i * D + j];
        __syncthreads();
        float accy = 0.f;
#pragma unroll 4
        for (int k = 0; k < D; k++) accy += xr[k] * Wl_a2c[k * D + j];
        ya_bf[i * D + j] = (unsigned short)bf16_rn(accy);
        return;
    }
    const float* pr = psum + (size_t)i * NRNG * D + j;
    float s = 0.f;
#pragma unroll
    for (int r = 0; r < NRNG; r++) s += pr[r * D];
    int deg = rp_ar[i * NRNG + NRNG] - rp_ar[i * NRNG];
    mr[j] = s / fmaxf((float)deg, 1.f);
    xr[j] = xa_old[i * D + j];
    __syncthreads();
    float accy = 0.f, accn = b_c2a[j];
#pragma unroll 4
    for (int k = 0; k < D; k++) {
        accy += xr[k] * Wl_a2c[k * D + j];
        accn += mr[k] * Wl_c2a[k * D + j] + xr[k] * Wr_c2a[k * D + j];
    }
    ya_bf[i * D + j] = (unsigned short)bf16_rn(accy);
    xa_out[i * D + j] = leaky(accn);
}

// FUSED gemm+agg. R9: gemm phase streams A+B per-kc from L2 (R5's gemm1, VGPR~48)
// instead of 64 persistent B-frag VGPRs that stay allocated through the agg phase.
// Occupancy tracks VGPR across rounds (40->53%, 52->35%, 84->28%); agg phase is
// byte-identical R4 (empirical optimum of 6 structural attempts).
#define ACC8(vv) do { \
    s0 += bf_lo(vv.x); s1 += bf_hi(vv.x); s2 += bf_lo(vv.y); s3 += bf_hi(vv.y); \
    s4 += bf_lo(vv.z); s5 += bf_hi(vv.z); s6 += bf_lo(vv.w); s7 += bf_hi(vv.w); } while (0)

#define GBLOCK(SRC) do { \
    int r0 = (SRC)[0], r1 = (SRC)[1], r2 = (SRC)[2], r3 = (SRC)[3]; \
    int r4 = (SRC)[4], r5 = (SRC)[5], r6 = (SRC)[6], r7 = (SRC)[7]; \
    uint4 v0 = ya4[(r0 << 4) + q]; uint4 v1 = ya4[(r1 << 4) + q]; \
    uint4 v2 = ya4[(r2 << 4) + q]; uint4 v3 = ya4[(r3 << 4) + q]; \
    uint4 v4 = ya4[(r4 << 4) + q]; uint4 v5 = ya4[(r5 << 4) + q]; \
    uint4 v6 = ya4[(r6 << 4) + q]; uint4 v7 = ya4[(r7 << 4) + q]; \
    ACC8(v0); ACC8(v1); ACC8(v2); ACC8(v3); \
    ACC8(v4); ACC8(v5); ACC8(v6); ACC8(v7); } while (0)

#define GTAIL(SRC) do { \
    int rr = (SRC)[0]; \
    uint4 v = ya4[(rr << 4) + q]; \
    ACC8(v); } while (0)

template <int LAST>
__global__ __launch_bounds__(256) void gemm_agg(const unsigned short* __restrict__ Ahi,
                                                const unsigned short* __restrict__ Alo,
                                                const unsigned short* __restrict__ Wt,
                                                const float* __restrict__ bias,
                                                const unsigned* __restrict__ ya,
                                                const int* __restrict__ rowptr,
                                                const int* __restrict__ col,
                                                unsigned* __restrict__ xhi,
                                                unsigned* __restrict__ xlo,
                                                const float* __restrict__ Wlin,
                                                const float* __restrict__ blin,
                                                float* __restrict__ out, int E) {
    __shared__ float smem[32][D];   // 16 KB tile of gemm output
    __shared__ int lcol[CAP_E];     // 6 KB col slice
    int tid = threadIdx.x;
    int wave = tid >> 6, lane = tid & 63;
    int cl = lane & 31, kh = lane >> 5;
    int n0 = wave * 32;
    int m0 = blockIdx.x * 32;
    int blkBeg = rowptr[m0], blkEnd = rowptr[m0 + 32];
    int nE = blkEnd - blkBeg;
    bool inlds = (nE <= CAP_E);
    // issue col-slice prefetch FIRST: its HBM latency hides under the whole gemm
    int pv[6];
#pragma unroll
    for (int k = 0; k < 6; k++) pv[k] = col[min(blkBeg + tid + k * 256, E - 1)];
    // gemm1: Y = xc @ W + bias, A and B streamed per-kc (no persistent frag VGPRs)
    float bv = bias[n0 + cl];
    f32x16 acc;
#pragma unroll
    for (int qq = 0; qq < 16; qq++) acc[qq] = bv;
    {
        const unsigned short* Wlo_ = Wt + D * D;
        const unsigned short* ar = Ahi + (size_t)(m0 + cl) * D + kh * 8;
        const unsigned short* al = Alo + (size_t)(m0 + cl) * D + kh * 8;
        const unsigned short* wh = Wt + (size_t)(n0 + cl) * D + kh * 8;
        const unsigned short* wl = Wlo_ + (size_t)(n0 + cl) * D + kh * 8;
#pragma unroll
        for (int kc = 0; kc < 8; kc++) {
            bf16x8 ahi = *(const bf16x8*)(ar + kc * 16);
            bf16x8 alo = *(const bf16x8*)(al + kc * 16);
            bf16x8 bh = *(const bf16x8*)(wh + kc * 16);
            bf16x8 bl = *(const bf16x8*)(wl + kc * 16);
            acc = __builtin_amdgcn_mfma_f32_32x32x16_bf16(ahi, bh, acc, 0, 0, 0);
            acc = __builtin_amdgcn_mfma_f32_32x32x16_bf16(alo, bh, acc, 0, 0, 0);
            acc = __builtin_amdgcn_mfma_f32_32x32x16_bf16(ahi, bl, acc, 0, 0, 0);
        }
    }
#pragma unroll
    for (int reg = 0; reg < 16; reg++) {
        int row = (reg & 3) + 8 * (reg >> 2) + 4 * kh;
        smem[row][n0 + cl] = acc[reg];   // 2 lanes/bank max -> conflict-free
    }
    // stash col slice (pv latency fully hidden by the gemm above)
    if (inlds) {
#pragma unroll
        for (int k = 0; k < 6; k++) lcol[tid + k * 256] = pv[k];
    }
    __syncthreads();
    // agg: 4 groups of 16 lanes per wave; group g owns client wave*8 + pass*4 + g.
    // Lane q covers dims 8q..8q+7 (one uint4 of the 64-word ya row). [R4-exact]
    const uint4* ya4 = (const uint4*)ya;
    int g = lane >> 4, q = lane & 15;
#pragma unroll
    for (int pass = 0; pass < 2; pass++) {
        int c_local = wave * 8 + pass * 4 + g;
        int gid = m0 + c_local;
        int beg = rowptr[gid], end = rowptr[gid + 1];
        int len = end - beg;
        float s0 = 0, s1 = 0, s2 = 0, s3 = 0, s4 = 0, s5 = 0, s6 = 0, s7 = 0;
        if (inlds) {
            const int* src = lcol + (beg - blkBeg);
            int j = 0;
            for (; j + 8 <= len; j += 8) GBLOCK(src + j);
            for (; j < len; j++) GTAIL(src + j);
        } else {
            const int* src = col + beg;
            int j = 0;
            for (; j + 8 <= len; j += 8) GBLOCK(src + j);
            for (; j < len; j++) GTAIL(src + j);
        }
        float inv = 1.f / fmaxf((float)len, 1.f);
        float4 y0 = *(const float4*)&smem[c_local][8 * q];
        float4 y1 = *(const float4*)&smem[c_local][8 * q + 4];
        float r0 = leaky(y0.x + s0 * inv);
        float r1 = leaky(y0.y + s1 * inv);
        float r2 = leaky(y0.z + s2 * inv);
        float r3 = leaky(y0.w + s3 * inv);
        float r4 = leaky(y1.x + s4 * inv);
        float r5 = leaky(y1.y + s5 * inv);
        float r6 = leaky(y1.z + s6 * inv);
        float r7 = leaky(y1.w + s7 * inv);
        if (LAST) {
            float4 w0 = *(const float4*)&Wlin[8 * q];
            float4 w1 = *(const float4*)&Wlin[8 * q + 4];
            float v = r0 * w0.x + r1 * w0.y + r2 * w0.z + r3 * w0.w +
                      r4 * w1.x + r5 * w1.y + r6 * w1.z + r7 * w1.w;
#pragma unroll
            for (int off = 8; off > 0; off >>= 1) v += __shfl_down(v, off, 16);
            if (q == 0) out[gid] = v + blin[0];
        } else {
            unsigned h0 = bf16_rn(r0), h1 = bf16_rn(r1), h2 = bf16_rn(r2), h3 = bf16_rn(r3);
            unsigned h4 = bf16_rn(r4), h5 = bf16_rn(r5), h6 = bf16_rn(r6), h7 = bf16_rn(r7);
            uint4 hi, lo;
            hi.x = h0 | (h1 << 16); hi.y = h2 | (h3 << 16);
            hi.z = h4 | (h5 << 16); hi.w = h6 | (h7 << 16);
            lo.x = pack_bf2(r0 - bf_val(h0), r1 - bf_val(h1));
            lo.y = pack_bf2(r2 - bf_val(h2), r3 - bf_val(h3));
            lo.z = pack_bf2(r4 - bf_val(h4), r5 - bf_val(h5));
            lo.w = pack_bf2(r6 - bf_val(h6), r7 - bf_val(h7));
            ((uint4*)xhi)[(gid << 4) + q] = hi;
            ((uint4*)xlo)[(gid << 4) + q] = lo;
        }
    }
}

extern "C" void kernel_launch(void* const* d_in, const int* in_sizes, int n_in,
                              void* d_out, int out_size, void* d_ws, size_t ws_size,
                              hipStream_t stream) {
    const float* x_clients = (const float*)d_in[0];
    const float* x_agg     = (const float*)d_in[1];
    const int*   c2a_src   = (const int*)d_in[2];
    const int*   c2a_dst   = (const int*)d_in[3];
    const int*   a2c_src   = (const int*)d_in[4];
    const int*   a2c_dst   = (const int*)d_in[5];
    const float* Wl_c2a    = (const float*)d_in[6];
    const float* Wr_c2a    = (const float*)d_in[7];
    const float* b_c2a     = (const float*)d_in[8];
    const float* Wl_a2c    = (const float*)d_in[9];
    const float* Wr_a2c    = (const float*)d_in[10];
    const float* b_a2c     = (const float*)d_in[11];
    const float* W_lin     = (const float*)d_in[12];
    const float* b_lin     = (const float*)d_in[13];
    float* out = (float*)d_out;
    const int E = in_sizes[2];

    char* p = (char*)d_ws;
    auto alloc = [&](size_t bytes) {
        char* r = p;
        p += (bytes + 255) & ~(size_t)255;
        return r;
    };
    float*    Yb    = (float*)alloc(sizeof(float) * NCLI * D);         // tmp1/tmp2 scratch only
    unsigned* xc_hi = (unsigned*)alloc(sizeof(unsigned) * NCLI * 64);  // bf16 hi (also gather tbl)
    unsigned* xc_lo = (unsigned*)alloc(sizeof(unsigned) * NCLI * 64);  // bf16 lo
    float*    xa    = (float*)alloc(sizeof(float) * NAGG * D);
    unsigned short* ya_bf = (unsigned short*)alloc(sizeof(unsigned short) * NAGG * D);
    unsigned short* Wt = (unsigned short*)alloc(sizeof(unsigned short) * NLAYER * 2 * D * D);
    float* psum  = (float*)alloc(sizeof(float) * NAGG * NRNG * D);     // 4 MB gather partials
    int* cnt_ar = (int*)alloc(sizeof(int) * (NBIN + NBKT));  // cnt_ar[0..7999] + bcnt
    int* bcnt  = cnt_ar + NBIN;
    int* rp_ar = (int*)alloc(sizeof(int) * (NBIN + 1));
    int* brp   = (int*)alloc(sizeof(int) * (NBKT + 1));
    int* bcur  = (int*)alloc(sizeof(int) * NBKT);
    int* ccur  = (int*)alloc(sizeof(int) * NC2A);
    int* rp_c  = (int*)alloc(sizeof(int) * (NCLI + 1));
    int* col_c2a = (int*)alloc(sizeof(int) * E);
    int* col_a2c = (int*)alloc(sizeof(int) * E);
    // tmp1/tmp2 alias Yb (12.8 MB needed, 51.2 MB available); lifetime ends before layers
    int* tmp1 = (int*)Yb;
    int* tmp2 = tmp1 + E;

    hipMemsetAsync(cnt_ar, 0, sizeof(int) * (NBIN + NBKT), stream);

    prep<<<NHIST + NCVTX + NCVTW, 256, 0, stream>>>(c2a_src, c2a_dst, a2c_dst, E, cnt_ar, bcnt,
                                                    (const float4*)x_clients,
                                                    (uint2*)xc_hi, (uint2*)xc_lo,
                                                    Wr_a2c, Wt);
    scan_both<<<2, 1024, 0, stream>>>(cnt_ar, rp_ar, bcnt, brp, bcur, ccur);
    scatter_coarse<<<512, 1024, 0, stream>>>(c2a_src, c2a_dst, a2c_src, a2c_dst, E,
                                             ccur, tmp1, bcur, tmp2);
    refine<<<NC2A + NBKT, 1024, 0, stream>>>(rp_ar, tmp1, col_c2a, brp, tmp2, rp_c, col_a2c);

    const float* xa_old = x_agg;
    for (int l = 0; l < NLAYER; l++) {
        if (l < NLAYER - 1) {
            // full agg-side update (mean needed for xa_out)
            gather_mean<<<(NAGG / 4) * NRNG, 512, 0, stream>>>(xc_hi, rp_ar, col_c2a, psum);
            combine_agg<0><<<NAGG, 128, 0, stream>>>(psum, rp_ar, xa_old,
                                                     Wl_a2c + l * D * D, Wl_c2a + l * D * D,
                                                     Wr_c2a + l * D * D, b_c2a + l * D,
                                                     ya_bf, xa);
            gemm_agg<0><<<NROWT, 256, 0, stream>>>(
                (const unsigned short*)xc_hi, (const unsigned short*)xc_lo,
                Wt + l * 2 * D * D, b_a2c + l * D, (const unsigned*)ya_bf, rp_c, col_a2c,
                xc_hi, xc_lo, nullptr, nullptr, nullptr, E);
        } else {
            // last layer: xa is dead (output = f(xc) only) -> skip gather_mean,
            // combine_agg computes only ya = xa_old @ Wl_a2c
            combine_agg<1><<<NAGG, 128, 0, stream>>>(psum, rp_ar, xa_old,
                                                     Wl_a2c + l * D * D, Wl_c2a + l * D * D,
                                                     Wr_c2a + l * D * D, b_c2a + l * D,
                                                     ya_bf, xa);
            gemm_agg<1><<<NROWT, 256, 0, stream>>>(
                (const unsigned short*)xc_hi, (const unsigned short*)xc_lo,
                Wt + l * 2 * D * D, b_a2c + l * D, (const unsigned*)ya_bf, rp_c, col_a2c,
                nullptr, nullptr, W_lin, b_lin, out, E);
        }
        xa_old = xa;
    }
}